// Round 1
// 512.410 us; speedup vs baseline: 1.0550x; 1.0550x over previous
//
#include <hip/hip_runtime.h>
#include <math.h>

#define T      512
#define NBATCH 512
#define IN_DIM 64
#define H      100
#define KP     208          // padded contraction: L1 = [x(64)|h1(100)|pad], L2 = [h1|h2|pad]
#define PBYTES 832          // KP*4 bytes: stride between parity buffers

// tanh(a) = 1 - 2/(exp(2a)+1)  -- overflow-safe at both ends.
__device__ __forceinline__ float fast_tanh(float a) {
    float e = __expf(2.0f * a);
    return 1.0f - 2.0f / (e + 1.0f);
}

// ---------------------------------------------------------------------------
// All-DPP 8-lane reduction. K-split lanes of a group differ in lane bits
// {0,1,3}; group id sits in bits {2,4,5}. xor1/xor2 = quad_perm (0xB1/0x4E),
// xor8 = row_ror:8 (0x128) -- all VALU, zero LDS-pipe traffic (the old
// __shfl_xor path emitted ds_swizzle for the >quad levels).
// ---------------------------------------------------------------------------
#define DPP_ADD(v, ctrl) ((v) + __int_as_float(__builtin_amdgcn_update_dpp( \
        0, __float_as_int(v), (ctrl), 0xF, 0xF, true)))
#define RED8(a) { (a) = DPP_ADD((a), 0xB1);   /* xor 1 */ \
                  (a) = DPP_ADD((a), 0x4E);   /* xor 2 */ \
                  (a) = DPP_ADD((a), 0x128);  /* xor 8 (row_ror:8) */ }

// weight element for concatenated row R: rows [0,kA) -> WA, [kA,kA+100) -> WB, else 0
__device__ __forceinline__ float wval(const float* __restrict__ WA,
                                      const float* __restrict__ WB,
                                      int kA, int R, int col) {
    if (R < kA) return WA[R * H + col];
    int rr = R - kA;
    return (rr < H) ? WB[rr * H + col] : 0.f;
}

__device__ __forceinline__ float4 wload4(const float* __restrict__ WA,
                                         const float* __restrict__ WB,
                                         int kA, int R0, int col) {
    return make_float4(wval(WA, WB, kA, R0 + 0, col),
                       wval(WA, WB, kA, R0 + 1, col),
                       wval(WA, WB, kA, R0 + 2, col),
                       wval(WA, WB, kA, R0 + 3, col));
}

// ---------------------------------------------------------------------------
// 512-thread block, one batch element. 50 packed groups of 8 lanes:
// groups 0-24 = layer-1 neurons (4 per group), 25-49 = layer-2 (pipelined one
// step behind), spread over waves 0-6. Wave 7 = dedicated x-prefetch wave.
// Per thread: 8-way K-split of KP=208 -> 26 weight floats per neuron-col x 4
// cols = 104 weight VGPRs (half of the old 208, so they genuinely fit under
// the 128-VGPR cap needed for 4 waves/SIMD = 16 waves/CU).
// Per DOT: 6 ds_read_b128 + 1 ds_read_b64, 104 FMAs, 12 DPP-adds.
// ---------------------------------------------------------------------------

#define RNDS(X) X(0) X(1) X(2) X(3) X(4) X(5)

#define WDECL(R) float4 w##R##_0 = {0,0,0,0}, w##R##_1 = {0,0,0,0}, \
                        w##R##_2 = {0,0,0,0}, w##R##_3 = {0,0,0,0};

#define WLOAD(R) { const int r0_ = 32 * (R) + 4 * s;   \
    w##R##_0 = wload4(WA, WB, kA, r0_, j + 0);         \
    w##R##_1 = wload4(WA, WB, kA, r0_, j + 1);         \
    w##R##_2 = wload4(WA, WB, kA, r0_, j + 2);         \
    w##R##_3 = wload4(WA, WB, kA, r0_, j + 3); }

#define FSTEP(R, P) { const float4 v_ = *(const float4*)(rb + (P) + 128 * (R)); \
    a0 = fmaf(v_.x, w##R##_0.x, a0); a1 = fmaf(v_.x, w##R##_1.x, a1);           \
    a2 = fmaf(v_.x, w##R##_2.x, a2); a3 = fmaf(v_.x, w##R##_3.x, a3);           \
    a0 = fmaf(v_.y, w##R##_0.y, a0); a1 = fmaf(v_.y, w##R##_1.y, a1);           \
    a2 = fmaf(v_.y, w##R##_2.y, a2); a3 = fmaf(v_.y, w##R##_3.y, a3);           \
    a0 = fmaf(v_.z, w##R##_0.z, a0); a1 = fmaf(v_.z, w##R##_1.z, a1);           \
    a2 = fmaf(v_.z, w##R##_2.z, a2); a3 = fmaf(v_.z, w##R##_3.z, a3);           \
    a0 = fmaf(v_.w, w##R##_0.w, a0); a1 = fmaf(v_.w, w##R##_1.w, a1);           \
    a2 = fmaf(v_.w, w##R##_2.w, a2); a3 = fmaf(v_.w, w##R##_3.w, a3); }

#define DOT(P, hv) {                                                 \
    float a0 = 0.f, a1 = 0.f, a2 = 0.f, a3 = 0.f;                    \
    FSTEP(0, P) FSTEP(1, P) FSTEP(2, P)                              \
    FSTEP(3, P) FSTEP(4, P) FSTEP(5, P)                              \
    { const float2 v_ = *(const float2*)(tb + (P));                  \
      a0 = fmaf(v_.x, wt0.x, a0); a1 = fmaf(v_.x, wt1.x, a1);        \
      a2 = fmaf(v_.x, wt2.x, a2); a3 = fmaf(v_.x, wt3.x, a3);        \
      a0 = fmaf(v_.y, wt0.y, a0); a1 = fmaf(v_.y, wt1.y, a1);        \
      a2 = fmaf(v_.y, wt2.y, a2); a3 = fmaf(v_.y, wt3.y, a3); }      \
    RED8(a0) RED8(a1) RED8(a2) RED8(a3)                              \
    const float t01_ = (s & 1) ? a1 : a0;                            \
    const float t23_ = (s & 1) ? a3 : a2;                            \
    hv = fast_tanh(((s & 2) ? t23_ : t01_) + bj); }

__global__ __launch_bounds__(512, 4)
void drnn_kernel(const float* __restrict__ x,
                 const float* __restrict__ W1x, const float* __restrict__ W1h,
                 const float* __restrict__ b1,
                 const float* __restrict__ W2x, const float* __restrict__ W2h,
                 const float* __restrict__ b2,
                 const float* __restrict__ Wo,  const float* __restrict__ bo,
                 float* __restrict__ out)
{
    // in1: [x_t (64) | h1 (100) | pad->208]; in2: [h1 (100) | h2 (100) | pad->208]
    __shared__ __align__(16) float in1[2][KP];
    __shared__ __align__(16) float in2[2][KP];

    const int tid  = threadIdx.x;
    const int b    = blockIdx.x;
    const int lane = tid & 63;
    const int wv   = tid >> 6;
    const int s    = (lane & 3) | ((lane >> 1) & 4);        // K-slice: lane bits {0,1,3}
    const int gw   = ((lane >> 2) & 1) | ((lane >> 3) & 6); // group-in-wave: bits {2,4,5}
    const int gg   = wv * 8 + gw;                           // global group 0..63
    const bool active = (gg < 50);                          // 25 L1 + 25 L2 groups
    const bool isL1   = (gg < 25);
    const bool isXL   = (wv == 7);                          // x-prefetch wave

    const float* __restrict__ xrow = x + (size_t)b * T * IN_DIM;

    // ---- zero-init LDS (pads stay 0; h(-1)=0; h2(-1) slot stays 0) ----
    for (int k = tid; k < 2 * KP; k += 512) {
        (&in1[0][0])[k] = 0.f;
        (&in2[0][0])[k] = 0.f;
    }
    if (tid < IN_DIM) in1[0][tid] = xrow[tid];   // x(0)

    const float* __restrict__ WA = isL1 ? W1x : W2x;
    const float* __restrict__ WB = isL1 ? W1h : W2h;
    const int kA = isL1 ? IN_DIM : H;            // rows [0,kA)->WA, [kA,kA+100)->WB
    const int gl = isL1 ? gg : gg - 25;
    const int nl = (gl >= 0 && gl < 25) ? gl : 0;
    const int j  = 4 * nl;                       // neuron base col (exact, no clamp: 4*24+3=99)
    const int n  = j + (s & 3);                  // neuron this lane finalizes/stores
    const float bj = active ? (isL1 ? b1 : b2)[n] : 0.f;

    // ---- 104 named weight floats: 24 float4 + 4 float2 (tail rows 192..207) ----
    RNDS(WDECL)
    float2 wt0 = {0,0}, wt1 = {0,0}, wt2 = {0,0}, wt3 = {0,0};
    if (active) {
        RNDS(WLOAD)
        const int rt = 192 + 2 * s;
        wt0 = make_float2(wval(WA,WB,kA,rt,j+0), wval(WA,WB,kA,rt+1,j+0));
        wt1 = make_float2(wval(WA,WB,kA,rt,j+1), wval(WA,WB,kA,rt+1,j+1));
        wt2 = make_float2(wval(WA,WB,kA,rt,j+2), wval(WA,WB,kA,rt+1,j+2));
        wt3 = make_float2(wval(WA,WB,kA,rt,j+3), wval(WA,WB,kA,rt+1,j+3));
    }

    // ---- per-lane LDS pointers; odd parity reached via +PBYTES immediate ----
    const char* lb = (const char*)(isL1 ? &in1[0][0] : &in2[0][0]);
    const char* rb = lb + 16 * s;               // round r at offset P + 128*r
    const char* tb = lb + 768 + 8 * s;          // float2 tail

    char* st;                                    // parity-0 store slot
    if (isL1) st = (char*)((s < 4) ? &in1[0][64 + n] : &in2[0][n]); // h1 -> both consumers
    else      st = (char*)&in2[0][100 + n];                          // h2 recurrent slot
    const bool dost = active && (isL1 || s < 4);

    char* xw = (char*)&in1[0][lane];             // x slot (wave 7 only)
    float xr0 = 0.f, xr1 = 0.f;
    if (isXL) {
        xr0 = xrow[IN_DIM + lane];               // x(1)
        xr1 = xrow[2 * IN_DIM + lane];           // x(2)
    }

    __syncthreads();

    // Body i: L1 computes h1(i); L2 computes h2(i-1). Wave 7 stages x(i+1).
    #pragma unroll 1
    for (int i = 0; i < T; i += 2) {
        // ---- even body: read parity 0, write parity 1 ----
        if (active) {
            float hv; DOT(0, hv)
            if (dost && (isL1 || i > 0)) *(float*)(st + PBYTES) = hv; // skip bogus h2(-1)
        } else if (isXL) {
            *(float*)(xw + PBYTES) = xr0;        // x(i+1)
            xr0 = xr1;
            if (i + 3 < T) xr1 = xrow[(size_t)(i + 3) * IN_DIM + lane];
        }
        __syncthreads();
        // ---- odd body: read parity 1, write parity 0 ----
        if (active) {
            float hv; DOT(PBYTES, hv)
            if (dost) *(float*)st = hv;
        } else if (isXL) {
            *(float*)xw = xr0;                   // x(i+2)
            xr0 = xr1;
            if (i + 4 < T) xr1 = xrow[(size_t)(i + 4) * IN_DIM + lane];
        }
        __syncthreads();
    }

    // ---- tail (parity 0): only L2, computes h2(T-1) from {h1(T-1), h2(T-2)} ----
    if (active && !isL1) {
        float hv; DOT(0, hv)
        if (s < 4) *(float*)(st + PBYTES) = hv;  // -> in2[1][100..]
    }
    __syncthreads();

    // ---- epilogue: h1(T-1) in in1[0][64..], h2(T-1) in in2[1][100..] ----
    if (tid < H)
        out[NBATCH + (size_t)b * H + tid] = in1[0][64 + tid];
    if (tid < H)
        out[NBATCH + (size_t)NBATCH * H + (size_t)b * H + tid] = in2[1][100 + tid];

    // out[b] = h2_T . Wo + bo  (wave-0 shuffle reduction)
    if (tid < 64) {
        float v = in2[1][100 + tid] * Wo[tid];
        if (tid + 64 < H) v += in2[1][100 + 64 + tid] * Wo[tid + 64];
        #pragma unroll
        for (int off = 32; off >= 1; off >>= 1) v += __shfl_down(v, off);
        if (tid == 0) out[b] = v + bo[0];
    }
}

extern "C" void kernel_launch(void* const* d_in, const int* in_sizes, int n_in,
                              void* d_out, int out_size, void* d_ws, size_t ws_size,
                              hipStream_t stream) {
    const float* x   = (const float*)d_in[0];
    const float* W1x = (const float*)d_in[1];
    const float* W1h = (const float*)d_in[2];
    const float* b1  = (const float*)d_in[3];
    const float* W2x = (const float*)d_in[4];
    const float* W2h = (const float*)d_in[5];
    const float* b2  = (const float*)d_in[6];
    const float* Wo  = (const float*)d_in[7];
    const float* bo  = (const float*)d_in[8];
    float* out = (float*)d_out;

    drnn_kernel<<<NBATCH, 512, 0, stream>>>(x, W1x, W1h, b1, W2x, W2h, b2,
                                            Wo, bo, out);
}